// Round 1
// baseline (158.704 us; speedup 1.0000x reference)
//
#include <hip/hip_runtime.h>
#include <stdint.h>

// Problem constants (from reference): B=4, CIN=COUT=256, H=W=64, 3x3, pad=1, stride=1
#define KDIM 2304   // CIN * 9, GEMM K
#define NTOT 16384  // B * Ho * Wo, GEMM N

typedef __bf16 bf16_t;
typedef bf16_t bf16x8 __attribute__((ext_vector_type(8)));
typedef float f32x4 __attribute__((ext_vector_type(4)));

__device__ __forceinline__ float b2f(uint32_t u) {
  union { uint32_t i; float f; } c; c.i = u << 16; return c.f;
}
// float -> bf16 bits, round-to-nearest-even
__device__ __forceinline__ uint32_t f2b(float f) {
  union { float f; uint32_t u; } c; c.f = f;
  uint32_t u = c.u;
  return (u + 0x7fffu + ((u >> 16) & 1u)) >> 16;
}

// async 16B global -> LDS (wave-uniform LDS base + lane*16 contract)
__device__ __forceinline__ void g2lds16(const uint16_t* g, uint16_t* l) {
  __builtin_amdgcn_global_load_lds((const __attribute__((address_space(1))) void*)g,
                                   (__attribute__((address_space(3))) void*)l,
                                   16, 0, 0);
}

// ---------------- kernel 1: x [4][256][64][64] f32  ->  xt [4][64][64][256] bf16
__global__ __launch_bounds__(256) void k_transpose(const float* __restrict__ x,
                                                   uint16_t* __restrict__ xt) {
  __shared__ float tile[32][33];
  int b = blockIdx.z;
  int c0 = blockIdx.y << 5;
  int s0 = blockIdx.x << 5;   // s = h*64+w
  int tx = threadIdx.x & 31, ty = threadIdx.x >> 5;
  const float* src = x + ((size_t)(b * 256 + c0)) * 4096 + s0;
#pragma unroll
  for (int i = 0; i < 4; ++i)
    tile[ty + i * 8][tx] = src[(size_t)(ty + i * 8) * 4096 + tx];
  __syncthreads();
#pragma unroll
  for (int i = 0; i < 4; ++i) {
    int s = s0 + ty + i * 8;
    int c = c0 + tx;
    xt[((size_t)b * 4096 + s) * 256 + c] = (uint16_t)f2b(tile[tx][ty + i * 8]);
  }
}

// ---------------- kernel 2: weight [256][256][3][3] f32 -> wt [cout][k*256+c] bf16
__global__ __launch_bounds__(256) void k_wprep(const float* __restrict__ w,
                                               uint16_t* __restrict__ wt) {
  int t = blockIdx.x * 256 + threadIdx.x;   // exactly 256*2304 threads
  int cout = t / KDIM;
  int r = t - cout * KDIM;
  int k = r >> 8, c = r & 255;
  wt[t] = (uint16_t)f2b(w[((size_t)(cout * 256 + c)) * 9 + k]);
}

// ---------------- kernel 3: bilinear-deform im2col -> cols [n][k*256+c] bf16
// one block per (b, ho); 1024 threads = 16 waves; each wave handles one (k,wo)
// sample across its 64 lanes (4 channels/lane).
__global__ __launch_bounds__(1024) void k_im2col(const uint16_t* __restrict__ xt,
                                                 const float* __restrict__ off,
                                                 const float* __restrict__ msk,
                                                 uint16_t* __restrict__ cols) {
  __shared__ float s_off[18 * 64];
  __shared__ float s_msk[9 * 64];
  int blk = blockIdx.x;
  int b = blk >> 6, ho = blk & 63;
  int tid = threadIdx.x;
  // stage this output row's offsets (18 ch) and masks (9 ch)
  for (int i = tid; i < 18 * 64; i += 1024) {
    int ch = i >> 6, wo = i & 63;
    s_off[i] = off[((size_t)(b * 18 + ch)) * 4096 + ho * 64 + wo];
  }
  for (int i = tid; i < 9 * 64; i += 1024) {
    int ch = i >> 6, wo = i & 63;
    s_msk[i] = msk[((size_t)(b * 9 + ch)) * 4096 + ho * 64 + wo];
  }
  __syncthreads();
  int wv = tid >> 6, lane = tid & 63;
  int c4 = lane << 2;
  const uint16_t* base = xt + (size_t)b * 4096 * 256;
  uint16_t* cbase = cols + ((size_t)b * 4096 + (size_t)ho * 64) * KDIM;
  for (int s = wv; s < 576; s += 16) {
    int k = s >> 6, wo = s & 63;
    int kh = k / 3, kw = k - kh * 3;
    float dy = s_off[(2 * k) * 64 + wo];
    float dx = s_off[(2 * k + 1) * 64 + wo];
    float mm = s_msk[k * 64 + wo];
    float sy = (float)(ho - 1 + kh) + dy;
    float sx = (float)(wo - 1 + kw) + dx;
    float fy = floorf(sy), fx = floorf(sx);
    int y0 = (int)fy, x0 = (int)fx;
    float wy = sy - fy, wx = sx - fx;
    float a0 = 0.f, a1 = 0.f, a2 = 0.f, a3 = 0.f;
#pragma unroll
    for (int cy = 0; cy < 2; ++cy) {
#pragma unroll
      for (int cx = 0; cx < 2; ++cx) {
        int y = y0 + cy, x = x0 + cx;
        float w = (cy ? wy : 1.f - wy) * (cx ? wx : 1.f - wx);
        bool v = ((unsigned)y < 64u) && ((unsigned)x < 64u);
        w = v ? w : 0.f;
        int yc = min(max(y, 0), 63), xc = min(max(x, 0), 63);
        const uint2 d = *(const uint2*)(base + (((size_t)yc * 64 + xc) * 256 + c4));
        a0 += w * b2f(d.x & 0xffffu);
        a1 += w * b2f(d.x >> 16);
        a2 += w * b2f(d.y & 0xffffu);
        a3 += w * b2f(d.y >> 16);
      }
    }
    a0 *= mm; a1 *= mm; a2 *= mm; a3 *= mm;
    uint2 o;
    o.x = f2b(a0) | (f2b(a1) << 16);
    o.y = f2b(a2) | (f2b(a3) << 16);
    *(uint2*)(cbase + (size_t)wo * KDIM + k * 256 + c4) = o;
  }
}

// ---------------- kernel 4: GEMM  C[m][n] = sum_k A[m][k] * B[n][k]
// A = wt [256][2304] bf16 (K-contig), B = cols [16384][2304] bf16 (K-contig)
// m97-style: 128x128 tile, BK=32, global_load_lds x16, 16x16x32 bf16 MFMA
#define BM 128
#define BN 128
#define BK 32
__global__ __launch_bounds__(256) void k_gemm(const uint16_t* __restrict__ A,
                                              const uint16_t* __restrict__ Bm,
                                              const float* __restrict__ bias,
                                              float* __restrict__ out) {
  __shared__ __align__(16) uint16_t As[BM * BK];
  __shared__ __align__(16) uint16_t Bs[BN * BK];
  int tid = threadIdx.x;
  int lane = tid & 63, wv = tid >> 6;
  int wm = wv >> 1, wn = wv & 1;            // 2x2 wave grid, 64x64 each
  int m0 = blockIdx.y * BM, n0 = blockIdx.x * BN;
  int q = lane >> 4, r = lane & 15;

  f32x4 acc[4][4];
#pragma unroll
  for (int i = 0; i < 4; ++i)
#pragma unroll
    for (int j = 0; j < 4; ++j) acc[i][j] = f32x4{0.f, 0.f, 0.f, 0.f};

  // staging: chunk = pass*256 + tid; row = chunk>>2; quad = chunk&3
  const uint16_t* a0p = A + (size_t)(m0 + (tid >> 2)) * KDIM + (tid & 3) * 8;
  const uint16_t* a1p = A + (size_t)(m0 + 64 + (tid >> 2)) * KDIM + (tid & 3) * 8;
  const uint16_t* b0p = Bm + (size_t)(n0 + (tid >> 2)) * KDIM + (tid & 3) * 8;
  const uint16_t* b1p = Bm + (size_t)(n0 + 64 + (tid >> 2)) * KDIM + (tid & 3) * 8;
  uint16_t* as0 = &As[tid * 8];
  uint16_t* as1 = &As[2048 + tid * 8];
  uint16_t* bs0 = &Bs[tid * 8];
  uint16_t* bs1 = &Bs[2048 + tid * 8];

  for (int k0 = 0; k0 < KDIM; k0 += BK) {
    g2lds16(a0p + k0, as0);
    g2lds16(a1p + k0, as1);
    g2lds16(b0p + k0, bs0);
    g2lds16(b1p + k0, bs1);
    __syncthreads();
    bf16x8 af[4], bfr[4];
#pragma unroll
    for (int mi = 0; mi < 4; ++mi)
      af[mi] = *(const bf16x8*)&As[(wm * 64 + mi * 16 + r) * BK + q * 8];
#pragma unroll
    for (int ni = 0; ni < 4; ++ni)
      bfr[ni] = *(const bf16x8*)&Bs[(wn * 64 + ni * 16 + r) * BK + q * 8];
#pragma unroll
    for (int mi = 0; mi < 4; ++mi)
#pragma unroll
      for (int ni = 0; ni < 4; ++ni)
        acc[mi][ni] = __builtin_amdgcn_mfma_f32_16x16x32_bf16(af[mi], bfr[ni], acc[mi][ni], 0, 0, 0);
    __syncthreads();
  }

  // epilogue: C/D layout col = lane&15 (n), row = q*4 + j (m)
#pragma unroll
  for (int mi = 0; mi < 4; ++mi) {
#pragma unroll
    for (int j = 0; j < 4; ++j) {
      int m = m0 + wm * 64 + mi * 16 + q * 4 + j;
      float bv = bias[m];
#pragma unroll
      for (int ni = 0; ni < 4; ++ni) {
        int n = n0 + wn * 64 + ni * 16 + r;
        int b = n >> 12, p = n & 4095;
        out[((size_t)(b * 256 + m)) * 4096 + p] = acc[mi][ni][j] + bv;
      }
    }
  }
}

extern "C" void kernel_launch(void* const* d_in, const int* in_sizes, int n_in,
                              void* d_out, int out_size, void* d_ws, size_t ws_size,
                              hipStream_t stream) {
  (void)in_sizes; (void)n_in; (void)out_size; (void)ws_size;
  const float* x      = (const float*)d_in[0];  // [4][256][64][64]
  const float* offset = (const float*)d_in[1];  // [4][18][64][64]
  const float* mask   = (const float*)d_in[2];  // [4][9][64][64]
  const float* weight = (const float*)d_in[3];  // [256][256][3][3]
  const float* bias   = (const float*)d_in[4];  // [256]
  float* out = (float*)d_out;                   // [4][256][64][64]

  uint8_t* ws = (uint8_t*)d_ws;
  uint16_t* xt   = (uint16_t*)ws;               // 8,388,608 B : NHWC bf16
  uint16_t* wt   = (uint16_t*)(ws + 8388608);   // 1,179,648 B : [cout][k*256+c]
  uint16_t* cols = (uint16_t*)(ws + 9568256);   // 75,497,472 B: [n][k*256+c]

  k_transpose<<<dim3(128, 8, 4), 256, 0, stream>>>(x, xt);
  k_wprep<<<dim3(2304), 256, 0, stream>>>(weight, wt);
  k_im2col<<<dim3(256), 1024, 0, stream>>>(xt, offset, mask, cols);
  k_gemm<<<dim3(128, 2), 256, 0, stream>>>(wt, cols, bias, out);
}